// Round 3
// baseline (1680.814 us; speedup 1.0000x reference)
//
#include <hip/hip_runtime.h>

#define NN 100000
#define NE 3200000
#define NB 391          // buckets of 256 nodes: ceil(NN/256)
#define CHUNK 8192      // edges per sorter/hist block
#define NBLK 391        // ceil(NE/CHUNK)
#define LN_EPS 1e-5f

// ---------------- bucket histogram (global counts per 256-node bucket) ----------------

__global__ __launch_bounds__(256) void k_hist(const int* __restrict__ dst, int* __restrict__ bcnt) {
  __shared__ int lh[NB];
  int tid = threadIdx.x;
  for (int i = tid; i < NB; i += 256) lh[i] = 0;
  __syncthreads();
  int base = blockIdx.x * CHUNK;
  #pragma unroll
  for (int k = 0; k < 32; ++k) {
    int e = base + tid + k * 256;
    if (e < NE) atomicAdd(&lh[dst[e] >> 8], 1);
  }
  __syncthreads();
  for (int i = tid; i < NB; i += 256)
    if (lh[i]) atomicAdd(&bcnt[i], lh[i]);
}

// ---------------- scan of 391 bucket counts -> offsets + cursors ----------------

__global__ __launch_bounds__(512) void k_scanb(const int* __restrict__ bcnt,
                                               int* __restrict__ boff, int* __restrict__ bcur) {
  __shared__ int s[512];
  int i = threadIdx.x;
  int c = (i < NB) ? bcnt[i] : 0;
  s[i] = c;
  __syncthreads();
  for (int off = 1; off < 512; off <<= 1) {
    int v = (i >= off) ? s[i - off] : 0;
    __syncthreads();
    s[i] += v;
    __syncthreads();
  }
  if (i < NB) {
    int excl = s[i] - c;
    boff[i] = excl;
    bcur[i] = excl;
  }
}

// ---------------- bucket sort: block-local counting sort, contiguous run writes ----------------

__global__ __launch_bounds__(256) void k_bucket(const int* __restrict__ src, const int* __restrict__ dst,
                                                int* __restrict__ bcur, unsigned* __restrict__ packed) {
  __shared__ int lh[NB];        // counts, then rank counters (back to counts after pass2)
  __shared__ int lstart[NB];    // exclusive scan (local)
  __shared__ int lg[NB];        // reserved global base per bucket
  __shared__ int sc[512];       // scan temp
  __shared__ unsigned buf[CHUNK];
  int tid = threadIdx.x;
  for (int i = tid; i < NB; i += 256) lh[i] = 0;
  __syncthreads();
  int base = blockIdx.x * CHUNK;
  // pass 1: local histogram
  #pragma unroll
  for (int k = 0; k < 32; ++k) {
    int e = base + tid + k * 256;
    if (e < NE) atomicAdd(&lh[dst[e] >> 8], 1);
  }
  __syncthreads();
  // local exclusive scan (512-wide Hillis-Steele, 2 slots/thread)
  int ia = tid, ib = tid + 256;
  sc[ia] = (ia < NB) ? lh[ia] : 0;
  sc[ib] = (ib < NB) ? lh[ib] : 0;
  __syncthreads();
  for (int off = 1; off < 512; off <<= 1) {
    int va = (ia >= off) ? sc[ia - off] : 0;
    int vb = (ib >= off) ? sc[ib - off] : 0;
    __syncthreads();
    sc[ia] += va;
    sc[ib] += vb;
    __syncthreads();
  }
  if (ia < NB) lstart[ia] = sc[ia] - lh[ia];
  if (ib < NB) lstart[ib] = sc[ib] - lh[ib];
  // reserve global space per bucket
  for (int i = tid; i < NB; i += 256) {
    int c = lh[i];
    lg[i] = c ? atomicAdd(&bcur[i], c) : 0;
  }
  __syncthreads();
  for (int i = tid; i < NB; i += 256) lh[i] = 0;   // reset as rank counters
  __syncthreads();
  // pass 2: rank + reorder into LDS (order within bucket irrelevant)
  #pragma unroll
  for (int k = 0; k < 32; ++k) {
    int e = base + tid + k * 256;
    if (e < NE) {
      int d = dst[e];
      int b = d >> 8;
      int r = atomicAdd(&lh[b], 1);
      buf[lstart[b] + r] = (unsigned)src[e] | ((unsigned)(d & 255) << 24);
    }
  }
  __syncthreads();
  // output: half-wave per bucket run -> coalesced contiguous writes
  int hw = tid >> 5, l = tid & 31;
  for (int b = hw; b < NB; b += 8) {
    int cnt = lh[b], st = lstart[b], gp = lg[b];
    for (int j = l; j < cnt; j += 32) packed[gp + j] = buf[st + j];
  }
}

// ---------------- per-bucket degree -> d^-1/2 ----------------

__global__ __launch_bounds__(256) void k_deg(const unsigned* __restrict__ packed,
                                             const int* __restrict__ boff, const int* __restrict__ bcnt,
                                             float* __restrict__ ds) {
  __shared__ int h[256];
  int tid = threadIdx.x;
  h[tid] = 0;
  __syncthreads();
  int b = blockIdx.x;
  int o = boff[b], e1 = o + bcnt[b];
  for (int i = o + tid; i < e1; i += 256) atomicAdd(&h[packed[i] >> 24], 1);
  __syncthreads();
  int n = b * 256 + tid;
  if (n < NN) ds[n] = rsqrtf((float)h[tid] + 1.0f);
}

// ---------------- GEMM1: xw1s = (x @ W1) * ds  (128 -> 32) ----------------

__global__ __launch_bounds__(256) void k_gemm1(const float* __restrict__ x, const float* __restrict__ W1,
                                               const float* __restrict__ ds, float* __restrict__ xw1s) {
  __shared__ float Wt[32][132];
  __shared__ float xr[8][128];
  for (int idx = threadIdx.x; idx < 4096; idx += 256) {
    int k = idx >> 5, c = idx & 31;
    Wt[c][k] = W1[idx];
  }
  __syncthreads();
  int g = threadIdx.x >> 5, lane = threadIdx.x & 31;
  for (int tile = blockIdx.x; tile < NN / 8; tile += gridDim.x) {
    int row = tile * 8 + g;
    float4 xv = *(const float4*)&x[row * 128 + lane * 4];
    *(float4*)&xr[g][lane * 4] = xv;
    __syncthreads();
    float acc = 0.f;
    #pragma unroll
    for (int k4 = 0; k4 < 32; ++k4) {
      float4 a = *(const float4*)&xr[g][k4 * 4];
      float4 b = *(const float4*)&Wt[lane][k4 * 4];
      acc = fmaf(a.x, b.x, acc);
      acc = fmaf(a.y, b.y, acc);
      acc = fmaf(a.z, b.z, acc);
      acc = fmaf(a.w, b.w, acc);
    }
    xw1s[row * 32 + lane] = acc * ds[row];
    __syncthreads();
  }
}

// ------- per-bucket: LDS-accumulate edges + self + bias -> LN -> ReLU -> @Wnext (scaled) -------

template <int NOUT>
__global__ __launch_bounds__(256) void k_agg(const float* __restrict__ xws, const unsigned* __restrict__ packed,
    const int* __restrict__ boff, const int* __restrict__ bcnt, const float* __restrict__ ds,
    const float* __restrict__ bias, const float* __restrict__ gam, const float* __restrict__ bet,
    const float* __restrict__ Wn, float* __restrict__ outs) {
  __shared__ float acc[256 * 32];
  __shared__ float Wl[1024];
  int tid = threadIdx.x;
  if (NOUT == 32) {
    for (int i = tid; i < 1024; i += 256) Wl[i] = Wn[i];
  }
  for (int i = tid; i < 8192; i += 256) acc[i] = 0.f;
  __syncthreads();
  int b = blockIdx.x;
  int o = boff[b], e1 = o + bcnt[b];
  int hw = tid >> 5, l = tid & 31;
  int i = o + hw;
  for (; i + 8 < e1; i += 16) {   // 2 edges in flight per half-wave
    unsigned e0 = packed[i];
    unsigned e1p = packed[i + 8];
    float v0 = xws[(e0 & 0xFFFFFF) * 32 + l];
    float v1 = xws[(e1p & 0xFFFFFF) * 32 + l];
    atomicAdd(&acc[(e0 >> 24) * 32 + l], v0);
    atomicAdd(&acc[(e1p >> 24) * 32 + l], v1);
  }
  for (; i < e1; i += 8) {
    unsigned e = packed[i];
    atomicAdd(&acc[(e >> 24) * 32 + l], xws[(e & 0xFFFFFF) * 32 + l]);
  }
  __syncthreads();
  // epilogue: 32 rows per half-wave
  int nb = b * 256;
  for (int dl = hw; dl < 256; dl += 8) {
    int n = nb + dl;
    if (n >= NN) break;
    float dsn = ds[n];
    float val = dsn * (acc[dl * 32 + l] + xws[n * 32 + l]) + bias[l];
    float sum = val;
    for (int o2 = 16; o2 > 0; o2 >>= 1) sum += __shfl_xor(sum, o2, 32);
    float mu = sum * (1.f / 32.f);
    float d = val - mu;
    float sq = d * d;
    for (int o2 = 16; o2 > 0; o2 >>= 1) sq += __shfl_xor(sq, o2, 32);
    float h = d * rsqrtf(sq * (1.f / 32.f) + LN_EPS) * gam[l] + bet[l];
    h = fmaxf(h, 0.f);   // ReLU (dropout = identity in eval)
    if (NOUT == 32) {
      float a2 = 0.f;
      #pragma unroll
      for (int c = 0; c < 32; ++c) {
        float hc = __shfl(h, c, 32);
        a2 = fmaf(hc, Wl[c * 32 + l], a2);
      }
      outs[n * 32 + l] = a2 * dsn;
    } else {
      float p0 = h * Wn[l * 2];
      float p1 = h * Wn[l * 2 + 1];
      for (int o2 = 16; o2 > 0; o2 >>= 1) { p0 += __shfl_xor(p0, o2, 32); p1 += __shfl_xor(p1, o2, 32); }
      if (l == 0) { outs[n * 2] = p0 * dsn; outs[n * 2 + 1] = p1 * dsn; }
    }
  }
}

// ---------------- final aggregation (2 channels) -> logits ----------------

__global__ __launch_bounds__(256) void k_agg2(const float* __restrict__ xws, const unsigned* __restrict__ packed,
    const int* __restrict__ boff, const int* __restrict__ bcnt, const float* __restrict__ ds,
    const float* __restrict__ b3, float* __restrict__ out) {
  __shared__ float acc[512];
  int tid = threadIdx.x;
  acc[tid] = 0.f;
  acc[tid + 256] = 0.f;
  __syncthreads();
  int b = blockIdx.x;
  int o = boff[b], e1 = o + bcnt[b];
  for (int i = o + tid; i < e1; i += 256) {
    unsigned e = packed[i];
    int s = e & 0xFFFFFF;
    int dl = e >> 24;
    float2 v = *(const float2*)&xws[s * 2];
    atomicAdd(&acc[dl * 2], v.x);
    atomicAdd(&acc[dl * 2 + 1], v.y);
  }
  __syncthreads();
  int n = b * 256 + tid;
  if (n < NN) {
    float dsn = ds[n];
    float2 sv = *(const float2*)&xws[n * 2];
    float2 r;
    r.x = dsn * (acc[tid * 2] + sv.x) + b3[0];
    r.y = dsn * (acc[tid * 2 + 1] + sv.y) + b3[1];
    *(float2*)&out[n * 2] = r;
  }
}

extern "C" void kernel_launch(void* const* d_in, const int* in_sizes, int n_in,
                              void* d_out, int out_size, void* d_ws, size_t ws_size,
                              hipStream_t stream) {
  (void)in_sizes; (void)n_in; (void)out_size; (void)ws_size;
  const float* x   = (const float*)d_in[0];
  const int*   ei  = (const int*)d_in[1];
  const float* W1  = (const float*)d_in[2];
  const float* b1  = (const float*)d_in[3];
  const float* g1  = (const float*)d_in[4];
  const float* be1 = (const float*)d_in[5];
  const float* W2  = (const float*)d_in[6];
  const float* b2  = (const float*)d_in[7];
  const float* g2  = (const float*)d_in[8];
  const float* be2 = (const float*)d_in[9];
  const float* W3  = (const float*)d_in[10];
  const float* b3  = (const float*)d_in[11];
  const int* src = ei;
  const int* dst = ei + NE;
  float* out = (float*)d_out;

  char* w = (char*)d_ws;
  int*      bcnt   = (int*)(w);
  int*      boff   = (int*)(w + 4096);
  int*      bcur   = (int*)(w + 8192);
  float*    ds     = (float*)(w + 16384);          // 400 KB
  unsigned* packed = (unsigned*)(w + (512u << 10)); // 12.8 MB
  float*    xw1s   = (float*)(w + (14u << 20));     // 12.8 MB
  float*    xw2s   = (float*)(w + (28u << 20));     // 12.8 MB
  float*    xw3s   = (float*)(w + (14u << 20));     // 0.8 MB, overlays dead xw1s

  hipMemsetAsync(bcnt, 0, NB * sizeof(int), stream);
  k_hist  <<<NBLK, 256, 0, stream>>>(dst, bcnt);
  k_scanb <<<1,    512, 0, stream>>>(bcnt, boff, bcur);
  k_bucket<<<NBLK, 256, 0, stream>>>(src, dst, bcur, packed);
  k_deg   <<<NB,   256, 0, stream>>>(packed, boff, bcnt, ds);
  k_gemm1 <<<2048, 256, 0, stream>>>(x, W1, ds, xw1s);
  k_agg<32><<<NB,  256, 0, stream>>>(xw1s, packed, boff, bcnt, ds, b1, g1, be1, W2, xw2s);
  k_agg<2> <<<NB,  256, 0, stream>>>(xw2s, packed, boff, bcnt, ds, b2, g2, be2, W3, xw3s);
  k_agg2  <<<NB,   256, 0, stream>>>(xw3s, packed, boff, bcnt, ds, b3, out);
}

// Round 5
// 1495.975 us; speedup vs baseline: 1.1236x; 1.1236x over previous
//
#include <hip/hip_runtime.h>

#define NN 100000
#define NE 3200000
#define NB2 1563        // buckets of 64 nodes: ceil(NN/64)
#define CHUNK 8192      // edges per sorter/hist block
#define NBLK 391        // ceil(NE/CHUNK)
#define LN_EPS 1e-5f

// ---------------- bucket histogram (global counts per 64-node bucket) ----------------

__global__ __launch_bounds__(256) void k_hist(const int* __restrict__ dst, int* __restrict__ bcnt) {
  __shared__ int lh[NB2];
  int tid = threadIdx.x;
  for (int i = tid; i < NB2; i += 256) lh[i] = 0;
  __syncthreads();
  int base = blockIdx.x * CHUNK;
  #pragma unroll
  for (int k = 0; k < 32; ++k) {
    int e = base + tid + k * 256;
    if (e < NE) atomicAdd(&lh[dst[e] >> 6], 1);
  }
  __syncthreads();
  for (int i = tid; i < NB2; i += 256)
    if (lh[i]) atomicAdd(&bcnt[i], lh[i]);
}

// ---------------- scan of 1563 bucket counts -> offsets + cursors ----------------

__global__ __launch_bounds__(1024) void k_scanb(const int* __restrict__ bcnt,
                                                int* __restrict__ boff, int* __restrict__ bcur) {
  __shared__ int s[2048];
  int t = threadIdx.x;
  int i0 = t, i1 = t + 1024;
  int c0 = (i0 < NB2) ? bcnt[i0] : 0;
  int c1 = (i1 < NB2) ? bcnt[i1] : 0;
  s[i0] = c0; s[i1] = c1;
  __syncthreads();
  for (int off = 1; off < 2048; off <<= 1) {
    int a = (i0 >= off) ? s[i0 - off] : 0;
    int b = (i1 >= off) ? s[i1 - off] : 0;
    __syncthreads();
    s[i0] += a; s[i1] += b;
    __syncthreads();
  }
  if (i0 < NB2) { int e = s[i0] - c0; boff[i0] = e; bcur[i0] = e; }
  if (i1 < NB2) { int e = s[i1] - c1; boff[i1] = e; bcur[i1] = e; }
}

// ---------------- bucket sort: block-local counting sort, contiguous run writes ----------------

__global__ __launch_bounds__(256) void k_bucket(const int* __restrict__ src, const int* __restrict__ dst,
                                                int* __restrict__ bcur, unsigned* __restrict__ packed) {
  __shared__ int lh[NB2];       // counts, then rank counters
  __shared__ int lstart[NB2];   // local exclusive scan
  __shared__ int lg[NB2];       // reserved global base per bucket
  __shared__ int sc[2048];      // scan temp
  __shared__ unsigned buf[CHUNK];
  int tid = threadIdx.x;
  for (int i = tid; i < NB2; i += 256) lh[i] = 0;
  __syncthreads();
  int base = blockIdx.x * CHUNK;
  // pass 1: local histogram
  #pragma unroll
  for (int k = 0; k < 32; ++k) {
    int e = base + tid + k * 256;
    if (e < NE) atomicAdd(&lh[dst[e] >> 6], 1);
  }
  __syncthreads();
  // local exclusive scan over 2048 slots (8 slots/thread Hillis-Steele)
  #pragma unroll
  for (int k = 0; k < 8; ++k) {
    int idx = tid + k * 256;
    sc[idx] = (idx < NB2) ? lh[idx] : 0;
  }
  __syncthreads();
  for (int off = 1; off < 2048; off <<= 1) {
    int v[8];
    #pragma unroll
    for (int k = 0; k < 8; ++k) {
      int idx = tid + k * 256;
      v[k] = (idx >= off) ? sc[idx - off] : 0;
    }
    __syncthreads();
    #pragma unroll
    for (int k = 0; k < 8; ++k) sc[tid + k * 256] += v[k];
    __syncthreads();
  }
  #pragma unroll
  for (int k = 0; k < 8; ++k) {
    int idx = tid + k * 256;
    if (idx < NB2) lstart[idx] = sc[idx] - lh[idx];
  }
  // reserve global space per bucket
  for (int i = tid; i < NB2; i += 256) {
    int c = lh[i];
    lg[i] = c ? atomicAdd(&bcur[i], c) : 0;
  }
  __syncthreads();
  for (int i = tid; i < NB2; i += 256) lh[i] = 0;   // reset as rank counters
  __syncthreads();
  // pass 2: rank + reorder into LDS
  #pragma unroll
  for (int k = 0; k < 32; ++k) {
    int e = base + tid + k * 256;
    if (e < NE) {
      int d = dst[e];
      int b = d >> 6;
      int r = atomicAdd(&lh[b], 1);
      buf[lstart[b] + r] = (unsigned)src[e] | ((unsigned)(d & 63) << 24);
    }
  }
  __syncthreads();
  // output: half-wave per bucket run -> contiguous writes
  int hw = tid >> 5, l = tid & 31;
  for (int b = hw; b < NB2; b += 8) {
    int cnt = lh[b], st = lstart[b], gp = lg[b];
    for (int j = l; j < cnt; j += 32) packed[gp + j] = buf[st + j];
  }
}

// ---------------- per-bucket degree -> d^-1/2 ----------------

__global__ __launch_bounds__(256) void k_deg(const unsigned* __restrict__ packed,
                                             const int* __restrict__ boff, const int* __restrict__ bcnt,
                                             float* __restrict__ ds) {
  __shared__ int h[64];
  int tid = threadIdx.x;
  if (tid < 64) h[tid] = 0;
  __syncthreads();
  int b = blockIdx.x;
  int o = boff[b], e1 = o + bcnt[b];
  for (int i = o + tid; i < e1; i += 256) atomicAdd(&h[(packed[i] >> 24) & 63], 1);
  __syncthreads();
  if (tid < 64) {
    int n = b * 64 + tid;
    if (n < NN) ds[n] = rsqrtf((float)h[tid] + 1.0f);
  }
}

// ---------------- GEMM1: xw1s = (x @ W1) * ds  (128 -> 32) ----------------

__global__ __launch_bounds__(256) void k_gemm1(const float* __restrict__ x, const float* __restrict__ W1,
                                               const float* __restrict__ ds, float* __restrict__ xw1s) {
  __shared__ float Wt[32][132];
  __shared__ float xr[8][128];
  for (int idx = threadIdx.x; idx < 4096; idx += 256) {
    int k = idx >> 5, c = idx & 31;
    Wt[c][k] = W1[idx];
  }
  __syncthreads();
  int g = threadIdx.x >> 5, lane = threadIdx.x & 31;
  for (int tile = blockIdx.x; tile < NN / 8; tile += gridDim.x) {
    int row = tile * 8 + g;
    float4 xv = *(const float4*)&x[row * 128 + lane * 4];
    *(float4*)&xr[g][lane * 4] = xv;
    __syncthreads();
    float acc = 0.f;
    #pragma unroll
    for (int k4 = 0; k4 < 32; ++k4) {
      float4 a = *(const float4*)&xr[g][k4 * 4];
      float4 b = *(const float4*)&Wt[lane][k4 * 4];
      acc = fmaf(a.x, b.x, acc);
      acc = fmaf(a.y, b.y, acc);
      acc = fmaf(a.z, b.z, acc);
      acc = fmaf(a.w, b.w, acc);
    }
    xw1s[row * 32 + lane] = acc * ds[row];
    __syncthreads();
  }
}

// ------- per-bucket: LDS-accumulate edges + self + bias -> LN -> ReLU -> @Wnext (scaled) -------

template <int NOUT>
__global__ __launch_bounds__(256) void k_agg(const float* __restrict__ xws, const unsigned* __restrict__ packed,
    const int* __restrict__ boff, const int* __restrict__ bcnt, const float* __restrict__ ds,
    const float* __restrict__ bias, const float* __restrict__ gam, const float* __restrict__ bet,
    const float* __restrict__ Wn, float* __restrict__ outs) {
  __shared__ float acc[64 * 32];
  __shared__ float Wl[1024];
  int tid = threadIdx.x;
  if (NOUT == 32) {
    for (int i = tid; i < 1024; i += 256) Wl[i] = Wn[i];
  }
  for (int i = tid; i < 2048; i += 256) acc[i] = 0.f;
  __syncthreads();
  int b = blockIdx.x;
  int o = boff[b], e1 = o + bcnt[b];
  int hw = tid >> 5, l = tid & 31;
  int i = o + hw;
  for (; i + 56 < e1; i += 64) {   // 8 independent gather chains per half-wave
    unsigned e[8];
    float v[8];
    #pragma unroll
    for (int k = 0; k < 8; ++k) e[k] = packed[i + k * 8];
    #pragma unroll
    for (int k = 0; k < 8; ++k) v[k] = xws[(e[k] & 0xFFFFFF) * 32 + l];
    #pragma unroll
    for (int k = 0; k < 8; ++k) atomicAdd(&acc[((e[k] >> 24) & 63) * 32 + l], v[k]);
  }
  for (; i < e1; i += 8) {
    unsigned e = packed[i];
    atomicAdd(&acc[((e >> 24) & 63) * 32 + l], xws[(e & 0xFFFFFF) * 32 + l]);
  }
  __syncthreads();
  // epilogue: 8 rows per half-wave
  int nb = b * 64;
  for (int dl = hw; dl < 64; dl += 8) {
    int n = nb + dl;
    if (n >= NN) break;
    float dsn = ds[n];
    float val = dsn * (acc[dl * 32 + l] + xws[n * 32 + l]) + bias[l];
    float sum = val;
    for (int o2 = 16; o2 > 0; o2 >>= 1) sum += __shfl_xor(sum, o2, 32);
    float mu = sum * (1.f / 32.f);
    float d = val - mu;
    float sq = d * d;
    for (int o2 = 16; o2 > 0; o2 >>= 1) sq += __shfl_xor(sq, o2, 32);
    float h = d * rsqrtf(sq * (1.f / 32.f) + LN_EPS) * gam[l] + bet[l];
    h = fmaxf(h, 0.f);   // ReLU (dropout = identity in eval)
    if (NOUT == 32) {
      float a2 = 0.f;
      #pragma unroll
      for (int c = 0; c < 32; ++c) {
        float hc = __shfl(h, c, 32);
        a2 = fmaf(hc, Wl[c * 32 + l], a2);
      }
      outs[n * 32 + l] = a2 * dsn;
    } else {
      float p0 = h * Wn[l * 2];
      float p1 = h * Wn[l * 2 + 1];
      for (int o2 = 16; o2 > 0; o2 >>= 1) { p0 += __shfl_xor(p0, o2, 32); p1 += __shfl_xor(p1, o2, 32); }
      if (l == 0) { outs[n * 2] = p0 * dsn; outs[n * 2 + 1] = p1 * dsn; }
    }
  }
}

// ---------------- final aggregation (2 channels) -> logits ----------------

__global__ __launch_bounds__(256) void k_agg2(const float* __restrict__ xws, const unsigned* __restrict__ packed,
    const int* __restrict__ boff, const int* __restrict__ bcnt, const float* __restrict__ ds,
    const float* __restrict__ b3, float* __restrict__ out) {
  __shared__ float acc[128];
  int tid = threadIdx.x;
  if (tid < 128) acc[tid] = 0.f;
  __syncthreads();
  int b = blockIdx.x;
  int o = boff[b], e1 = o + bcnt[b];
  for (int i = o + tid; i < e1; i += 256) {
    unsigned e = packed[i];
    int s = e & 0xFFFFFF;
    int dl = (e >> 24) & 63;
    float2 v = *(const float2*)&xws[s * 2];
    atomicAdd(&acc[dl * 2], v.x);
    atomicAdd(&acc[dl * 2 + 1], v.y);
  }
  __syncthreads();
  if (tid < 64) {
    int n = b * 64 + tid;
    if (n < NN) {
      float dsn = ds[n];
      float2 sv = *(const float2*)&xws[n * 2];
      float2 r;
      r.x = dsn * (acc[tid * 2] + sv.x) + b3[0];
      r.y = dsn * (acc[tid * 2 + 1] + sv.y) + b3[1];
      *(float2*)&out[n * 2] = r;
    }
  }
}

extern "C" void kernel_launch(void* const* d_in, const int* in_sizes, int n_in,
                              void* d_out, int out_size, void* d_ws, size_t ws_size,
                              hipStream_t stream) {
  (void)in_sizes; (void)n_in; (void)out_size; (void)ws_size;
  const float* x   = (const float*)d_in[0];
  const int*   ei  = (const int*)d_in[1];
  const float* W1  = (const float*)d_in[2];
  const float* b1  = (const float*)d_in[3];
  const float* g1  = (const float*)d_in[4];
  const float* be1 = (const float*)d_in[5];
  const float* W2  = (const float*)d_in[6];
  const float* b2  = (const float*)d_in[7];
  const float* g2  = (const float*)d_in[8];
  const float* be2 = (const float*)d_in[9];
  const float* W3  = (const float*)d_in[10];
  const float* b3  = (const float*)d_in[11];
  const int* src = ei;
  const int* dst = ei + NE;
  float* out = (float*)d_out;

  char* w = (char*)d_ws;
  int*      bcnt   = (int*)(w);                     // 6.3 KB
  int*      boff   = (int*)(w + 8192);              // 6.3 KB
  int*      bcur   = (int*)(w + 16384);             // 6.3 KB
  float*    ds     = (float*)(w + 32768);           // 400 KB
  unsigned* packed = (unsigned*)(w + (512u << 10)); // 12.8 MB
  float*    xw1s   = (float*)(w + (14u << 20));     // 12.8 MB
  float*    xw2s   = (float*)(w + (28u << 20));     // 12.8 MB
  float*    xw3s   = (float*)(w + (14u << 20));     // 0.8 MB, overlays dead xw1s

  hipMemsetAsync(bcnt, 0, NB2 * sizeof(int), stream);
  k_hist  <<<NBLK, 256,  0, stream>>>(dst, bcnt);
  k_scanb <<<1,    1024, 0, stream>>>(bcnt, boff, bcur);
  k_bucket<<<NBLK, 256,  0, stream>>>(src, dst, bcur, packed);
  k_deg   <<<NB2,  256,  0, stream>>>(packed, boff, bcnt, ds);
  k_gemm1 <<<2048, 256,  0, stream>>>(x, W1, ds, xw1s);
  k_agg<32><<<NB2, 256,  0, stream>>>(xw1s, packed, boff, bcnt, ds, b1, g1, be1, W2, xw2s);
  k_agg<2> <<<NB2, 256,  0, stream>>>(xw2s, packed, boff, bcnt, ds, b2, g2, be2, W3, xw3s);
  k_agg2  <<<NB2,  256,  0, stream>>>(xw3s, packed, boff, bcnt, ds, b3, out);
}

// Round 6
// 407.957 us; speedup vs baseline: 4.1201x; 3.6670x over previous
//
#include <hip/hip_runtime.h>

#define NN 100000
#define NE 3200000
#define NB2 1563        // buckets of 64 nodes: ceil(NN/64)
#define CHUNK 8192      // edges per sorter/hist block
#define NBLK 391        // ceil(NE/CHUNK)
#define LN_EPS 1e-5f

// ---------------- bucket histogram (global counts per 64-node bucket) ----------------

__global__ __launch_bounds__(256) void k_hist(const int* __restrict__ dst, int* __restrict__ bcnt) {
  __shared__ int lh[NB2];
  int tid = threadIdx.x;
  for (int i = tid; i < NB2; i += 256) lh[i] = 0;
  __syncthreads();
  int base = blockIdx.x * CHUNK;
  #pragma unroll
  for (int k = 0; k < 32; ++k) {
    int e = base + tid + k * 256;
    if (e < NE) atomicAdd(&lh[dst[e] >> 6], 1);
  }
  __syncthreads();
  for (int i = tid; i < NB2; i += 256)
    if (lh[i]) atomicAdd(&bcnt[i], lh[i]);
}

// ---------------- scan of 1563 bucket counts -> offsets + cursors ----------------

__global__ __launch_bounds__(1024) void k_scanb(const int* __restrict__ bcnt,
                                                int* __restrict__ boff, int* __restrict__ bcur,
                                                int* __restrict__ noff) {
  __shared__ int s[2048];
  int t = threadIdx.x;
  int i0 = t, i1 = t + 1024;
  int c0 = (i0 < NB2) ? bcnt[i0] : 0;
  int c1 = (i1 < NB2) ? bcnt[i1] : 0;
  s[i0] = c0; s[i1] = c1;
  __syncthreads();
  for (int off = 1; off < 2048; off <<= 1) {
    int a = (i0 >= off) ? s[i0 - off] : 0;
    int b = (i1 >= off) ? s[i1 - off] : 0;
    __syncthreads();
    s[i0] += a; s[i1] += b;
    __syncthreads();
  }
  if (i0 < NB2) { int e = s[i0] - c0; boff[i0] = e; bcur[i0] = e; }
  if (i1 < NB2) { int e = s[i1] - c1; boff[i1] = e; bcur[i1] = e; }
  if (t == 0) noff[NN] = NE;   // CSR sentinel
}

// ---------------- bucket sort: block-local counting sort, contiguous run writes ----------------

__global__ __launch_bounds__(256) void k_bucket(const int* __restrict__ src, const int* __restrict__ dst,
                                                int* __restrict__ bcur, unsigned* __restrict__ packed) {
  __shared__ int lh[NB2];       // counts, then rank counters
  __shared__ int lstart[NB2];   // local exclusive scan
  __shared__ int lg[NB2];       // reserved global base per bucket
  __shared__ int sc[2048];      // scan temp
  __shared__ unsigned buf[CHUNK];
  int tid = threadIdx.x;
  for (int i = tid; i < NB2; i += 256) lh[i] = 0;
  __syncthreads();
  int base = blockIdx.x * CHUNK;
  // pass 1: local histogram
  #pragma unroll
  for (int k = 0; k < 32; ++k) {
    int e = base + tid + k * 256;
    if (e < NE) atomicAdd(&lh[dst[e] >> 6], 1);
  }
  __syncthreads();
  // local exclusive scan over 2048 slots (8 slots/thread Hillis-Steele)
  #pragma unroll
  for (int k = 0; k < 8; ++k) {
    int idx = tid + k * 256;
    sc[idx] = (idx < NB2) ? lh[idx] : 0;
  }
  __syncthreads();
  for (int off = 1; off < 2048; off <<= 1) {
    int v[8];
    #pragma unroll
    for (int k = 0; k < 8; ++k) {
      int idx = tid + k * 256;
      v[k] = (idx >= off) ? sc[idx - off] : 0;
    }
    __syncthreads();
    #pragma unroll
    for (int k = 0; k < 8; ++k) sc[tid + k * 256] += v[k];
    __syncthreads();
  }
  #pragma unroll
  for (int k = 0; k < 8; ++k) {
    int idx = tid + k * 256;
    if (idx < NB2) lstart[idx] = sc[idx] - lh[idx];
  }
  // reserve global space per bucket
  for (int i = tid; i < NB2; i += 256) {
    int c = lh[i];
    lg[i] = c ? atomicAdd(&bcur[i], c) : 0;
  }
  __syncthreads();
  for (int i = tid; i < NB2; i += 256) lh[i] = 0;   // reset as rank counters
  __syncthreads();
  // pass 2: rank + reorder into LDS
  #pragma unroll
  for (int k = 0; k < 32; ++k) {
    int e = base + tid + k * 256;
    if (e < NE) {
      int d = dst[e];
      int b = d >> 6;
      int r = atomicAdd(&lh[b], 1);
      buf[lstart[b] + r] = (unsigned)src[e] | ((unsigned)(d & 63) << 24);
    }
  }
  __syncthreads();
  // output: half-wave per bucket run -> contiguous writes
  int hw = tid >> 5, l = tid & 31;
  for (int b = hw; b < NB2; b += 8) {
    int cnt = lh[b], st = lstart[b], gp = lg[b];
    for (int j = l; j < cnt; j += 32) packed[gp + j] = buf[st + j];
  }
}

// ------- per-bucket node sort: packed (bucket-sorted) -> per-node CSR + noff + ds -------

__global__ __launch_bounds__(256) void k_nodesort(const unsigned* __restrict__ packed,
                                                  const int* __restrict__ boff, const int* __restrict__ bcnt,
                                                  int* __restrict__ csr, int* __restrict__ noff,
                                                  float* __restrict__ ds) {
  __shared__ int h[64], lstart[64], cur[64];
  int tid = threadIdx.x;
  if (tid < 64) h[tid] = 0;
  __syncthreads();
  int b = blockIdx.x;
  int o = boff[b], e1 = o + bcnt[b];
  for (int i = o + tid; i < e1; i += 256) atomicAdd(&h[(packed[i] >> 24) & 63], 1);
  __syncthreads();
  if (tid < 64) {   // wave 0: 64-lane inclusive scan -> exclusive
    int c = h[tid];
    int x = c;
    #pragma unroll
    for (int off = 1; off < 64; off <<= 1) {
      int t = __shfl_up(x, off);
      if (tid >= off) x += t;
    }
    int ex = x - c;
    lstart[tid] = ex;
    cur[tid] = 0;
    int n = b * 64 + tid;
    if (n < NN) {
      noff[n] = o + ex;
      ds[n] = rsqrtf((float)c + 1.0f);
    }
  }
  __syncthreads();
  for (int i = o + tid; i < e1; i += 256) {
    unsigned e = packed[i];
    int dl = (e >> 24) & 63;
    int r = atomicAdd(&cur[dl], 1);
    csr[o + lstart[dl] + r] = (int)(e & 0xFFFFFF);   // writes stay inside bucket's 8KB region
  }
}

// ---------------- GEMM1: xw1s = (x @ W1) * ds  (128 -> 32) ----------------

__global__ __launch_bounds__(256) void k_gemm1(const float* __restrict__ x, const float* __restrict__ W1,
                                               const float* __restrict__ ds, float* __restrict__ xw1s) {
  __shared__ float Wt[32][132];
  __shared__ float xr[8][128];
  for (int idx = threadIdx.x; idx < 4096; idx += 256) {
    int k = idx >> 5, c = idx & 31;
    Wt[c][k] = W1[idx];
  }
  __syncthreads();
  int g = threadIdx.x >> 5, lane = threadIdx.x & 31;
  for (int tile = blockIdx.x; tile < NN / 8; tile += gridDim.x) {
    int row = tile * 8 + g;
    float4 xv = *(const float4*)&x[row * 128 + lane * 4];
    *(float4*)&xr[g][lane * 4] = xv;
    __syncthreads();
    float acc = 0.f;
    #pragma unroll
    for (int k4 = 0; k4 < 32; ++k4) {
      float4 a = *(const float4*)&xr[g][k4 * 4];
      float4 b = *(const float4*)&Wt[lane][k4 * 4];
      acc = fmaf(a.x, b.x, acc);
      acc = fmaf(a.y, b.y, acc);
      acc = fmaf(a.z, b.z, acc);
      acc = fmaf(a.w, b.w, acc);
    }
    xw1s[row * 32 + lane] = acc * ds[row];
    __syncthreads();
  }
}

// ------- per-node register gather + self + bias -> LN -> ReLU -> @Wnext (scaled) -------

template <int NOUT>
__global__ __launch_bounds__(256, 4) void k_csragg(const float* __restrict__ xws, const int* __restrict__ csr,
    const int* __restrict__ noff, const float* __restrict__ ds,
    const float* __restrict__ bias, const float* __restrict__ gam, const float* __restrict__ bet,
    const float* __restrict__ Wn, float* __restrict__ outs) {
  __shared__ float Wl[1024];
  int tid = threadIdx.x;
  if (NOUT == 32) {
    for (int i = tid; i < 1024; i += 256) Wl[i] = Wn[i];
    __syncthreads();
  }
  int hw = tid >> 5, l = tid & 31;
  int n = blockIdx.x * 8 + hw;     // grid exact: NN/8 = 12500
  int o = noff[n], end = noff[n + 1];
  float a0 = 0.f, a1 = 0.f;
  int i = o;
  for (; i + 8 <= end; i += 8) {   // 8 independent gathers, 2 acc chains
    int s[8];
    #pragma unroll
    for (int k = 0; k < 8; ++k) s[k] = csr[i + k];
    float v[8];
    #pragma unroll
    for (int k = 0; k < 8; ++k) v[k] = xws[s[k] * 32 + l];
    #pragma unroll
    for (int k = 0; k < 8; ++k) { if (k & 1) a1 += v[k]; else a0 += v[k]; }
  }
  for (; i < end; ++i) a0 += xws[csr[i] * 32 + l];
  float dsn = ds[n];
  float val = dsn * (a0 + a1 + xws[n * 32 + l]) + bias[l];
  // LayerNorm over 32 channels in this half-wave
  float sum = val;
  for (int o2 = 16; o2 > 0; o2 >>= 1) sum += __shfl_xor(sum, o2, 32);
  float mu = sum * (1.f / 32.f);
  float d = val - mu;
  float sq = d * d;
  for (int o2 = 16; o2 > 0; o2 >>= 1) sq += __shfl_xor(sq, o2, 32);
  float h = d * rsqrtf(sq * (1.f / 32.f) + LN_EPS) * gam[l] + bet[l];
  h = fmaxf(h, 0.f);   // ReLU (dropout = identity in eval)
  if (NOUT == 32) {
    float a2 = 0.f;
    #pragma unroll
    for (int c = 0; c < 32; ++c) {
      float hc = __shfl(h, c, 32);
      a2 = fmaf(hc, Wl[c * 32 + l], a2);
    }
    outs[n * 32 + l] = a2 * dsn;
  } else {
    float p0 = h * Wn[l * 2];
    float p1 = h * Wn[l * 2 + 1];
    for (int o2 = 16; o2 > 0; o2 >>= 1) { p0 += __shfl_xor(p0, o2, 32); p1 += __shfl_xor(p1, o2, 32); }
    if (l == 0) { outs[n * 2] = p0 * dsn; outs[n * 2 + 1] = p1 * dsn; }
  }
}

// ---------------- final aggregation (2 channels) -> logits ----------------

__global__ __launch_bounds__(256) void k_fin2(const float* __restrict__ xws, const int* __restrict__ csr,
    const int* __restrict__ noff, const float* __restrict__ ds,
    const float* __restrict__ b3, float* __restrict__ out) {
  int tid = threadIdx.x;
  int hw = tid >> 5, l = tid & 31;
  int n = blockIdx.x * 8 + hw;
  int o = noff[n], end = noff[n + 1];
  float a0 = 0.f, a1 = 0.f;
  for (int i = o + l; i < end; i += 32) {   // lanes stride edges, coalesced csr reads
    int s = csr[i];
    float2 v = *(const float2*)&xws[s * 2];
    a0 += v.x; a1 += v.y;
  }
  for (int o2 = 16; o2 > 0; o2 >>= 1) { a0 += __shfl_xor(a0, o2, 32); a1 += __shfl_xor(a1, o2, 32); }
  if (l == 0) {
    float dsn = ds[n];
    float2 sv = *(const float2*)&xws[n * 2];
    out[n * 2]     = dsn * (a0 + sv.x) + b3[0];
    out[n * 2 + 1] = dsn * (a1 + sv.y) + b3[1];
  }
}

extern "C" void kernel_launch(void* const* d_in, const int* in_sizes, int n_in,
                              void* d_out, int out_size, void* d_ws, size_t ws_size,
                              hipStream_t stream) {
  (void)in_sizes; (void)n_in; (void)out_size; (void)ws_size;
  const float* x   = (const float*)d_in[0];
  const int*   ei  = (const int*)d_in[1];
  const float* W1  = (const float*)d_in[2];
  const float* b1  = (const float*)d_in[3];
  const float* g1  = (const float*)d_in[4];
  const float* be1 = (const float*)d_in[5];
  const float* W2  = (const float*)d_in[6];
  const float* b2  = (const float*)d_in[7];
  const float* g2  = (const float*)d_in[8];
  const float* be2 = (const float*)d_in[9];
  const float* W3  = (const float*)d_in[10];
  const float* b3  = (const float*)d_in[11];
  const int* src = ei;
  const int* dst = ei + NE;
  float* out = (float*)d_out;

  char* w = (char*)d_ws;
  int*      bcnt   = (int*)(w);                      // 6.3 KB
  int*      boff   = (int*)(w + 8192);               // 6.3 KB
  int*      bcur   = (int*)(w + 16384);              // 6.3 KB
  int*      noff   = (int*)(w + 32768);              // 400 KB (NN+1)
  float*    ds     = (float*)(w + (448u << 10));     // 400 KB
  unsigned* packed = (unsigned*)(w + (1u << 20));    // 12.8 MB (dead after k_nodesort)
  int*      csr    = (int*)(w + (14u << 20));        // 12.8 MB
  float*    xw1s   = (float*)(w + (1u << 20));       // 12.8 MB, overlays dead packed
  float*    xw2s   = (float*)(w + (27u << 20));      // 12.8 MB
  float*    xw3s   = (float*)(w + (1u << 20));       // 0.8 MB, overlays dead xw1s

  hipMemsetAsync(bcnt, 0, NB2 * sizeof(int), stream);
  k_hist    <<<NBLK,  256,  0, stream>>>(dst, bcnt);
  k_scanb   <<<1,     1024, 0, stream>>>(bcnt, boff, bcur, noff);
  k_bucket  <<<NBLK,  256,  0, stream>>>(src, dst, bcur, packed);
  k_nodesort<<<NB2,   256,  0, stream>>>(packed, boff, bcnt, csr, noff, ds);
  k_gemm1   <<<2048,  256,  0, stream>>>(x, W1, ds, xw1s);
  k_csragg<32><<<NN/8, 256, 0, stream>>>(xw1s, csr, noff, ds, b1, g1, be1, W2, xw2s);
  k_csragg<2> <<<NN/8, 256, 0, stream>>>(xw2s, csr, noff, ds, b2, g2, be2, W3, xw3s);
  k_fin2    <<<NN/8,  256,  0, stream>>>(xw3s, csr, noff, ds, b3, out);
}